// Round 1
// baseline (4261.642 us; speedup 1.0000x reference)
//
#include <hip/hip_runtime.h>

#define B_ 4
#define C_ 2048
#define N_ 2304   // 48*48
#define D_ 256

// ---------------------------------------------------------------------------
// proj: Y[b,n,d] = sum_c X[b,c,n] * W[d,c] + bias[d]
// X: [B,C,N] (n contiguous), W: [D,C] (c contiguous), Y: [B,N,D] (d contiguous)
// tile 64(n) x 64(d) x 16(c), 256 threads, 4x4 per thread
// ---------------------------------------------------------------------------
__global__ __launch_bounds__(256) void proj_kernel(
    const float* __restrict__ X, const float* __restrict__ W,
    const float* __restrict__ bias, float* __restrict__ Y)
{
    const int b  = blockIdx.z;
    const int n0 = blockIdx.x * 64;
    const int d0 = blockIdx.y * 64;
    const int tid = threadIdx.x;
    const int tx = tid & 15, ty = tid >> 4;

    __shared__ float Xs[16][68];   // [c][n], +4 pad (float4-aligned, bank-spread)
    __shared__ float Ws[16][68];   // [c][d]

    float acc[4][4] = {};

    for (int c0 = 0; c0 < C_; c0 += 16) {
        {   // Xs[k][n] = X[b, c0+k, n0+n]  (coalesced float4 along n)
            const int k  = tid >> 4;
            const int nq = (tid & 15) << 2;
            const float4 v = *(const float4*)&X[((size_t)b*C_ + (c0+k))*N_ + n0 + nq];
            *(float4*)&Xs[k][nq] = v;
        }
        {   // Ws[k][d] = W[d0+d, c0+k]  (float4 along c, transposed into LDS)
            const int d  = tid >> 2;
            const int kq = (tid & 3) << 2;
            const float4 v = *(const float4*)&W[(size_t)(d0+d)*C_ + c0 + kq];
            Ws[kq+0][d] = v.x; Ws[kq+1][d] = v.y; Ws[kq+2][d] = v.z; Ws[kq+3][d] = v.w;
        }
        __syncthreads();
        #pragma unroll
        for (int k = 0; k < 16; ++k) {
            const float4 a = *(const float4*)&Xs[k][ty << 2];
            const float4 w = *(const float4*)&Ws[k][tx << 2];
            const float av[4] = {a.x, a.y, a.z, a.w};
            const float wv[4] = {w.x, w.y, w.z, w.w};
            #pragma unroll
            for (int i = 0; i < 4; ++i)
                #pragma unroll
                for (int j = 0; j < 4; ++j)
                    acc[i][j] += av[i] * wv[j];
        }
        __syncthreads();
    }

    const float4 bb = *(const float4*)&bias[d0 + (tx << 2)];
    #pragma unroll
    for (int i = 0; i < 4; ++i) {
        float4 o;
        o.x = acc[i][0] + bb.x; o.y = acc[i][1] + bb.y;
        o.z = acc[i][2] + bb.z; o.w = acc[i][3] + bb.w;
        *(float4*)&Y[((size_t)b*N_ + n0 + (ty<<2) + i)*D_ + d0 + (tx<<2)] = o;
    }
}

// ---------------------------------------------------------------------------
// scores: S[n,m] = sum_d Q[b,n,d] * K[b,m,d]   (per batch b)
// ---------------------------------------------------------------------------
__global__ __launch_bounds__(256) void scores_kernel(
    const float* __restrict__ Q, const float* __restrict__ K,
    float* __restrict__ S, int b)
{
    const int n0 = blockIdx.x * 64;
    const int m0 = blockIdx.y * 64;
    const int tid = threadIdx.x;
    const int tx = tid & 15, ty = tid >> 4;

    __shared__ float Qs[16][68];   // [d][n]
    __shared__ float Ks[16][68];   // [d][m]

    float acc[4][4] = {};

    for (int d0 = 0; d0 < D_; d0 += 16) {
        {   // transpose-load: float4 along d, scatter to [d][row]
            const int r  = tid >> 2;
            const int kq = (tid & 3) << 2;
            const float4 v = *(const float4*)&Q[((size_t)b*N_ + n0 + r)*D_ + d0 + kq];
            Qs[kq+0][r] = v.x; Qs[kq+1][r] = v.y; Qs[kq+2][r] = v.z; Qs[kq+3][r] = v.w;
            const float4 u = *(const float4*)&K[((size_t)b*N_ + m0 + r)*D_ + d0 + kq];
            Ks[kq+0][r] = u.x; Ks[kq+1][r] = u.y; Ks[kq+2][r] = u.z; Ks[kq+3][r] = u.w;
        }
        __syncthreads();
        #pragma unroll
        for (int k = 0; k < 16; ++k) {
            const float4 a = *(const float4*)&Qs[k][ty << 2];
            const float4 w = *(const float4*)&Ks[k][tx << 2];
            const float av[4] = {a.x, a.y, a.z, a.w};
            const float wv[4] = {w.x, w.y, w.z, w.w};
            #pragma unroll
            for (int i = 0; i < 4; ++i)
                #pragma unroll
                for (int j = 0; j < 4; ++j)
                    acc[i][j] += av[i] * wv[j];
        }
        __syncthreads();
    }

    #pragma unroll
    for (int i = 0; i < 4; ++i) {
        float4 o; o.x = acc[i][0]; o.y = acc[i][1]; o.z = acc[i][2]; o.w = acc[i][3];
        *(float4*)&S[(size_t)(n0 + (ty<<2) + i)*N_ + m0 + (tx<<2)] = o;
    }
}

// ---------------------------------------------------------------------------
// softmax over rows of S [N_, N_] in place; one block per row
// ---------------------------------------------------------------------------
__global__ __launch_bounds__(256) void softmax_kernel(float* __restrict__ S)
{
    float* row = S + (size_t)blockIdx.x * N_;
    const int tid = threadIdx.x;
    __shared__ float red[256];

    float m = -3.4e38f;
    for (int i = tid; i < N_; i += 256) m = fmaxf(m, row[i]);
    red[tid] = m; __syncthreads();
    for (int s = 128; s > 0; s >>= 1) {
        if (tid < s) red[tid] = fmaxf(red[tid], red[tid + s]);
        __syncthreads();
    }
    m = red[0]; __syncthreads();

    float sum = 0.f;
    for (int i = tid; i < N_; i += 256) {
        const float e = __expf(row[i] - m);
        row[i] = e;
        sum += e;
    }
    red[tid] = sum; __syncthreads();
    for (int s = 128; s > 0; s >>= 1) {
        if (tid < s) red[tid] += red[tid + s];
        __syncthreads();
    }
    const float inv = 1.0f / red[0];
    for (int i = tid; i < N_; i += 256) row[i] *= inv;
}

// ---------------------------------------------------------------------------
// out: O[b, 2048 + c, n] = sum_m A[n,m] * V[b,c,m]   (per batch b)
// A: [N,N] (m contiguous), V: [B,C,N] (m contiguous), O: [B, 4096, N]
// tile 64(c) x 64(n) x 16(m)
// ---------------------------------------------------------------------------
__global__ __launch_bounds__(256) void out_kernel(
    const float* __restrict__ A, const float* __restrict__ V,
    float* __restrict__ O, int b)
{
    const int c0 = blockIdx.x * 64;
    const int n0 = blockIdx.y * 64;
    const int tid = threadIdx.x;
    const int tx = tid & 15, ty = tid >> 4;

    __shared__ float Vs[16][68];   // [m][c]
    __shared__ float As[16][68];   // [m][n]

    float acc[4][4] = {};

    for (int m0 = 0; m0 < N_; m0 += 16) {
        {
            const int r  = tid >> 2;
            const int kq = (tid & 3) << 2;
            const float4 v = *(const float4*)&V[((size_t)b*C_ + c0 + r)*N_ + m0 + kq];
            Vs[kq+0][r] = v.x; Vs[kq+1][r] = v.y; Vs[kq+2][r] = v.z; Vs[kq+3][r] = v.w;
            const float4 u = *(const float4*)&A[(size_t)(n0 + r)*N_ + m0 + kq];
            As[kq+0][r] = u.x; As[kq+1][r] = u.y; As[kq+2][r] = u.z; As[kq+3][r] = u.w;
        }
        __syncthreads();
        #pragma unroll
        for (int k = 0; k < 16; ++k) {
            const float4 a = *(const float4*)&Vs[k][ty << 2];   // rows = c
            const float4 w = *(const float4*)&As[k][tx << 2];   // cols = n
            const float av[4] = {a.x, a.y, a.z, a.w};
            const float wv[4] = {w.x, w.y, w.z, w.w};
            #pragma unroll
            for (int i = 0; i < 4; ++i)
                #pragma unroll
                for (int j = 0; j < 4; ++j)
                    acc[i][j] += av[i] * wv[j];
        }
        __syncthreads();
    }

    #pragma unroll
    for (int i = 0; i < 4; ++i) {
        float4 o; o.x = acc[i][0]; o.y = acc[i][1]; o.z = acc[i][2]; o.w = acc[i][3];
        *(float4*)&O[((size_t)b*(2*C_) + C_ + c0 + (ty<<2) + i)*N_ + n0 + (tx<<2)] = o;
    }
}

// ---------------------------------------------------------------------------
// copy pass-through features X [B,C,N] -> O[b, 0..C, n] where O is [B,2C,N]
// ---------------------------------------------------------------------------
__global__ __launch_bounds__(256) void copy_kernel(
    const float4* __restrict__ X, float4* __restrict__ O)
{
    const size_t perb = (size_t)C_ * N_ / 4;
    const size_t i = (size_t)blockIdx.x * 256 + threadIdx.x;
    const size_t b = i / perb, r = i - b * perb;
    O[b * 2 * perb + r] = X[i];
}

extern "C" void kernel_launch(void* const* d_in, const int* in_sizes, int n_in,
                              void* d_out, int out_size, void* d_ws, size_t ws_size,
                              hipStream_t stream)
{
    const float* left  = (const float*)d_in[0];
    const float* right = (const float*)d_in[1];
    const float* wq    = (const float*)d_in[2];
    const float* bq    = (const float*)d_in[3];
    const float* wr    = (const float*)d_in[4];
    const float* br    = (const float*)d_in[5];
    float* out = (float*)d_out;
    float* ws  = (float*)d_ws;

    // workspace layout (floats): Q [B*N*D] | K [B*N*D] | S [N*N] (per-batch reuse)
    float* Q  = ws;
    float* Kp = Q  + (size_t)B_ * N_ * D_;
    float* S  = Kp + (size_t)B_ * N_ * D_;

    float* out1 = out;                              // left_attended  [B,2C,N]
    float* out2 = out + (size_t)B_ * 2 * C_ * N_;   // right_attended [B,2C,N]

    const dim3 blk(256);
    const dim3 gproj(N_/64, D_/64, B_);
    const dim3 gsc(N_/64, N_/64);
    const dim3 gout(C_/64, N_/64);
    const int  gcopy = (B_ * C_ * N_ / 4) / 256;    // 18432, exact

    // pass-through halves
    copy_kernel<<<gcopy, blk, 0, stream>>>((const float4*)left,  (float4*)out1);
    copy_kernel<<<gcopy, blk, 0, stream>>>((const float4*)right, (float4*)out2);

    // co-attend 1: query=left, ref=right  -> weighted_r into out1 channels [C,2C)
    proj_kernel<<<gproj, blk, 0, stream>>>(left,  wq, bq, Q);
    proj_kernel<<<gproj, blk, 0, stream>>>(right, wr, br, Kp);
    for (int b = 0; b < B_; ++b) {
        scores_kernel<<<gsc, blk, 0, stream>>>(Q, Kp, S, b);
        softmax_kernel<<<N_, blk, 0, stream>>>(S);
        out_kernel<<<gout, blk, 0, stream>>>(S, right, out1, b);
    }

    // co-attend 2: query=right, ref=left -> weighted_l into out2 channels [C,2C)
    proj_kernel<<<gproj, blk, 0, stream>>>(right, wq, bq, Q);
    proj_kernel<<<gproj, blk, 0, stream>>>(left,  wr, br, Kp);
    for (int b = 0; b < B_; ++b) {
        scores_kernel<<<gsc, blk, 0, stream>>>(Q, Kp, S, b);
        softmax_kernel<<<N_, blk, 0, stream>>>(S);
        out_kernel<<<gout, blk, 0, stream>>>(S, left, out2, b);
    }
}